// Round 1
// 256.553 us; speedup vs baseline: 1.1097x; 1.1097x over previous
//
#include <hip/hip_runtime.h>

#define GLOBAL_AS __attribute__((address_space(1)))
#define LDS_AS __attribute__((address_space(3)))

typedef unsigned short u16;
typedef unsigned int u32;
typedef __bf16 bf16x8 __attribute__((ext_vector_type(8)));
typedef float f32x4 __attribute__((ext_vector_type(4)));

static constexpr int BB = 8;        // batch
static constexpr int TT = 2048;     // time
static constexpr int DD = 1024;     // feature dim
static constexpr int MM = BB * TT;  // 16384 rows
static constexpr int KK = DD;       // 1024
static constexpr int NC = 64;       // scan chunks per sequence
static constexpr int CL = TT / NC;  // 32 timesteps per chunk
static constexpr int NCH = BB * NC; // 512 total chunks

__device__ __forceinline__ u16 f2bf(float f) {
  union { float f; u32 u; } c; c.f = f;
  u32 u = c.u;
  u32 r = (u + 0x7fffu + ((u >> 16) & 1u)) >> 16;  // RNE
  return (u16)r;
}

// ---------------- pass 0a: x fp32 -> bf16 ----------------
__global__ void cvt_x_kernel(const float* __restrict__ x, u16* __restrict__ xb) {
  int i = (blockIdx.x * blockDim.x + threadIdx.x) * 8;
  const float4* p = reinterpret_cast<const float4*>(x + i);
  float4 v0 = p[0], v1 = p[1];
  u16 r0 = f2bf(v0.x), r1 = f2bf(v0.y), r2 = f2bf(v0.z), r3 = f2bf(v0.w);
  u16 r4 = f2bf(v1.x), r5 = f2bf(v1.y), r6 = f2bf(v1.z), r7 = f2bf(v1.w);
  uint4 o;
  o.x = (u32)r0 | ((u32)r1 << 16);
  o.y = (u32)r2 | ((u32)r3 << 16);
  o.z = (u32)r4 | ((u32)r5 << 16);
  o.w = (u32)r6 | ((u32)r7 << 16);
  *reinterpret_cast<uint4*>(xb + i) = o;
}

// ---------------- pass 0b: W fp32 [k][n] -> bf16 W^T [n][k] ----------------
__global__ void cvt_w_kernel(const float* __restrict__ Wz, const float* __restrict__ Wh,
                             u16* __restrict__ WT) {
  __shared__ float tile[32][33];
  int w = blockIdx.z;
  const float* W = w ? Wh : Wz;
  u16* O = WT + (size_t)w * DD * KK;
  int k0 = blockIdx.y * 32;
  int n0 = blockIdx.x * 32;
  int tx = threadIdx.x, ty = threadIdx.y;
  for (int i = 0; i < 32; i += 8)
    tile[ty + i][tx] = W[(size_t)(k0 + ty + i) * DD + n0 + tx];
  __syncthreads();
  for (int i = 0; i < 32; i += 8)
    O[(size_t)(n0 + ty + i) * KK + k0 + tx] = f2bf(tile[tx][ty + i]);
}

// ---------------- pass 1: dual GEMM + gate epilogue + fused chunk-reduce ----------------
// Tile: 128 rows x 128 cols PER GEMM (z and h), BK=64, 4 waves in 2x2.
// Wave tile 64x64 per GEMM -> 64 MFMA vs 24 ds_read_b128 per K-iter (MFMA-dominant).
// LDS XOR-swizzle (elem ^= (row&7)<<3) applied both-sides (rule #21):
//   global_load_lds keeps a LINEAR LDS dest; the per-lane GLOBAL source carries
//   the inverse swizzle (per-thread constant ((tid&7)^((tid>>3)&7))<<3);
//   fragment ds_reads apply the same XOR. Kills the 8-way conflicts (1.05e7/disp).
// XCD swizzle: nwg=1024, bit-permute so each XCD sweeps nt fast / mt slow ->
//   A-panel fetched once per XCD, WT (4MB) L2-resident.
__global__ __launch_bounds__(256, 2) void gemm_dual_kernel(
    const u16* __restrict__ xb,   // [MM][KK] bf16
    const u16* __restrict__ WT,   // [2][DD][KK] bf16 (n-major)
    const float* __restrict__ bz, const float* __restrict__ bh,
    float* __restrict__ a_out, float* __restrict__ bb_out,
    float* __restrict__ Asum, float* __restrict__ Bsum) {
  __shared__ __align__(16) u16 As[128 * 64];
  __shared__ __align__(16) u16 Bzs[128 * 64];
  __shared__ __align__(16) u16 Bhs[128 * 64];

  // XCD-aware swizzle: bid -> swz so XCD x (bid%8==x) gets contiguous swz chunk
  int bid = blockIdx.x;
  int swz = ((bid & 7) << 7) | (bid >> 3);   // bijective (bit permutation)
  int mt = swz >> 3;    // 128 m-tiles
  int nt = swz & 7;     // 8 n-tiles of 128
  int m0 = mt * 128, n0 = nt * 128;

  int tid = threadIdx.x;
  int lane = tid & 63;
  int wave = tid >> 6;
  int wr = wave >> 1;   // wave row 0..1  (owns rows wr*64..wr*64+63)
  int wc = wave & 1;    // wave col 0..1  (owns cols wc*64..wc*64+63)

  // staging: thread's linear LDS dest for issue q is byte  tid*16 + q*4096
  //   -> row r = (tid>>3) + q*32, col-byte = (tid&7)*16, then inverse-swizzled.
  int r0 = tid >> 3;                                    // 0..31
  int cswz = ((tid & 7) ^ ((tid >> 3) & 7)) << 3;       // swizzled col (elems)
  const u16* Ag  = xb + (size_t)(m0 + r0) * KK + cswz;
  const u16* Bzg = WT + (size_t)(n0 + r0) * KK + cswz;
  const u16* Bhg = Bzg + (size_t)DD * KK;

  u16* AsW  = As  + wave * 512;   // wave-uniform base; HW adds lane*16B
  u16* BzsW = Bzs + wave * 512;
  u16* BhsW = Bhs + wave * 512;

  f32x4 accz[4][4];   // [i: 16-row frag][j: 16-col frag]
  f32x4 acch[4][4];
  for (int i = 0; i < 4; i++)
    for (int j = 0; j < 4; j++) {
      accz[i][j] = (f32x4){0.f, 0.f, 0.f, 0.f};
      acch[i][j] = (f32x4){0.f, 0.f, 0.f, 0.f};
    }

  int fr = lane & 15;
  int fk = (lane >> 4) * 8;
  const int swx = (fr & 7) << 3;   // read-side XOR (elems); row&7 == fr&7 here

  for (int k0i = 0; k0i < KK; k0i += 64) {
#pragma unroll
    for (int q = 0; q < 4; q++) {
      __builtin_amdgcn_global_load_lds((const GLOBAL_AS void*)(Ag  + k0i + (size_t)(q * 32) * KK),
                                       (LDS_AS void*)(AsW + q * 2048), 16, 0, 0);
      __builtin_amdgcn_global_load_lds((const GLOBAL_AS void*)(Bzg + k0i + (size_t)(q * 32) * KK),
                                       (LDS_AS void*)(BzsW + q * 2048), 16, 0, 0);
      __builtin_amdgcn_global_load_lds((const GLOBAL_AS void*)(Bhg + k0i + (size_t)(q * 32) * KK),
                                       (LDS_AS void*)(BhsW + q * 2048), 16, 0, 0);
    }
    __syncthreads();  // drains vmcnt -> staging visible

#pragma unroll
    for (int kk = 0; kk < 64; kk += 32) {
      bf16x8 af[4], bzf[4], bhf[4];
      for (int i = 0; i < 4; i++)
        af[i] = *reinterpret_cast<const bf16x8*>(
            As + (wr * 64 + i * 16 + fr) * 64 + ((kk + fk) ^ swx));
      for (int j = 0; j < 4; j++) {
        int br = wc * 64 + j * 16 + fr;
        bzf[j] = *reinterpret_cast<const bf16x8*>(Bzs + br * 64 + ((kk + fk) ^ swx));
        bhf[j] = *reinterpret_cast<const bf16x8*>(Bhs + br * 64 + ((kk + fk) ^ swx));
      }
      for (int i = 0; i < 4; i++)
        for (int j = 0; j < 4; j++) {
          accz[i][j] = __builtin_amdgcn_mfma_f32_16x16x32_bf16(af[i], bzf[j], accz[i][j], 0, 0, 0);
          acch[i][j] = __builtin_amdgcn_mfma_f32_16x16x32_bf16(af[i], bhf[j], acch[i][j], 0, 0, 0);
        }
    }
    __syncthreads();  // tiles consumed before restage
  }

  // epilogue: D[row = m0 + wr*64 + i*16 + quad*4 + r][col = n0 + wc*64 + j*16 + fr]
  // wave owns 64 rows = 2 scan chunks (CL=32): chunk ic composed from i=2ic,2ic+1
  int quad = lane >> 4;
  for (int j = 0; j < 4; j++) {
    int n = n0 + wc * 64 + j * 16 + fr;
    float bzv = bz[n], bhv = bh[n];
    float Ai[4], Bi[4];
    for (int i = 0; i < 4; i++) {
      float Aloc = 1.f, Bloc = 0.f;
      int mbase = m0 + wr * 64 + i * 16 + quad * 4;
      for (int r = 0; r < 4; r++) {
        float zp = accz[i][j][r] + bzv;
        float hp = acch[i][j][r] + bhv;
        float zs = 1.0f / (1.0f + __expf(-zp));
        float av = 1.0f - zs;
        float bv = zs * hp;
        size_t idx = (size_t)(mbase + r) * DD + n;
        a_out[idx] = av;
        bb_out[idx] = bv;
        Bloc = av * Bloc + bv;   // t-ascending composition
        Aloc = av * Aloc;
      }
      // ordered cross-quad combine (quads hold rows quad*4..quad*4+3 in the 16-row frag)
      float Ao = __shfl_xor(Aloc, 16, 64);
      float Bo = __shfl_xor(Bloc, 16, 64);
      float Bc = (quad & 1) ? (Aloc * Bo + Bloc) : (Ao * Bloc + Bo);
      float Ac = Aloc * Ao;
      float Ao2 = __shfl_xor(Ac, 32, 64);
      float Bo2 = __shfl_xor(Bc, 32, 64);
      Bi[i] = (quad & 2) ? (Ac * Bo2 + Bc) : (Ao2 * Bc + Bo2);
      Ai[i] = Ac * Ao2;
    }
    // chunk summaries: ic=0 -> frags i0,i1 (rows 0..31), ic=1 -> frags i2,i3
#pragma unroll
    for (int ic = 0; ic < 2; ic++) {
      float Ack = Ai[2 * ic + 1] * Ai[2 * ic];
      float Bck = Ai[2 * ic + 1] * Bi[2 * ic] + Bi[2 * ic + 1];
      if (quad == 0) {
        int cg = mt * 4 + wr * 2 + ic;   // global chunk id = (m0 + wr*64 + ic*32)/32
        Asum[(size_t)cg * DD + n] = Ack;
        Bsum[(size_t)cg * DD + n] = Bck;
      }
    }
  }
}

// ---------------- pass 2: scan over chunk summaries -> h_in per chunk ----------------
__global__ void chunk_scan_kernel(const float* __restrict__ Asum, const float* __restrict__ Bsum,
                                  float* __restrict__ hin) {
  int tid = blockIdx.x * blockDim.x + threadIdx.x;  // 8192 = [b][d]
  int d = tid & (DD - 1);
  int b = tid >> 10;
  float h = 0.f;
#pragma unroll
  for (int c = 0; c < NC; c++) {
    int i = (b * NC + c) * DD + d;
    hin[i] = h;
    h = Asum[i] * h + Bsum[i];
  }
}

// ---------------- pass 3: apply recurrence + swish + fused LayerNorm ----------------
// One BLOCK (4 waves, 256 threads) per chunk; lane owns one float4 of D.
// t-loop FULLY UNROLLED so the prefetch-ring / LDS-slot indices are compile-time
// constants -> everything stays in VGPRs (the round-1/2 version's runtime ring
// index forced the arrays to scratch, which dominated total time).
__global__ __launch_bounds__(256) void apply_ln_kernel(
    const float* __restrict__ a, const float* __restrict__ bb, const float* __restrict__ hin,
    const float* __restrict__ sbeta, const float* __restrict__ gamma,
    const float* __restrict__ lbeta, float* __restrict__ out) {
  __shared__ float ps[2][4];
  __shared__ float pq[2][4];
  int ch = blockIdx.x;                 // chunk id 0..511
  int wv = threadIdx.x >> 6;
  int lane = threadIdx.x & 63;
  int d = wv * 256 + lane * 4;
  int b = ch >> 6, c = ch & (NC - 1);
  float sb = sbeta[0];

  float4 g4 = *reinterpret_cast<const float4*>(gamma + d);
  float4 be4 = *reinterpret_cast<const float4*>(lbeta + d);
  float4 h4 = *reinterpret_cast<const float4*>(hin + (size_t)ch * DD + d);

  size_t base = ((size_t)b * TT + (size_t)c * CL) * DD + d;  // + t*DD

  // depth-3 prefetch ring (statically indexed after full unroll)
  float4 aR[3], bR[3];
#pragma unroll
  for (int p = 0; p < 3; p++) {
    aR[p] = *reinterpret_cast<const float4*>(a + base + (size_t)p * DD);
    bR[p] = *reinterpret_cast<const float4*>(bb + base + (size_t)p * DD);
  }

#pragma unroll
  for (int t = 0; t < CL; t++) {
    const int slot = t % 3;
    const int pslot = t & 1;
    float4 av = aR[slot], bv = bR[slot];
    h4.x = av.x * h4.x + bv.x;
    h4.y = av.y * h4.y + bv.y;
    h4.z = av.z * h4.z + bv.z;
    h4.w = av.w * h4.w + bv.w;
    if (t + 3 < CL) {  // refill ring; overlaps the reduction below
      aR[slot] = *reinterpret_cast<const float4*>(a + base + (size_t)(t + 3) * DD);
      bR[slot] = *reinterpret_cast<const float4*>(bb + base + (size_t)(t + 3) * DD);
    }
    float sx = sb * h4.x, sy = sb * h4.y, sz = sb * h4.z, sw = sb * h4.w;
    float4 y;
    y.x = sx / (1.0f + __expf(-sx));
    y.y = sy / (1.0f + __expf(-sy));
    y.z = sz / (1.0f + __expf(-sz));
    y.w = sw / (1.0f + __expf(-sw));
    float sum = y.x + y.y + y.z + y.w;
    float sq = y.x * y.x + y.y * y.y + y.z * y.z + y.w * y.w;
#pragma unroll
    for (int o = 32; o > 0; o >>= 1) {
      sum += __shfl_xor(sum, o, 64);
      sq += __shfl_xor(sq, o, 64);
    }
    if (lane == 0) { ps[pslot][wv] = sum; pq[pslot][wv] = sq; }
    __syncthreads();
    float tot = ps[pslot][0] + ps[pslot][1] + ps[pslot][2] + ps[pslot][3];
    float totq = pq[pslot][0] + pq[pslot][1] + pq[pslot][2] + pq[pslot][3];
    float mu = tot * (1.0f / DD);
    float var = totq * (1.0f / DD) - mu * mu;
    float inv = rsqrtf(fmaxf(var, 0.f) + 1e-5f);
    float4 o4;
    o4.x = (y.x - mu) * inv * g4.x + be4.x;
    o4.y = (y.y - mu) * inv * g4.y + be4.y;
    o4.z = (y.z - mu) * inv * g4.z + be4.z;
    o4.w = (y.w - mu) * inv * g4.w + be4.w;
    *reinterpret_cast<float4*>(out + base + (size_t)t * DD) = o4;
  }
}

extern "C" void kernel_launch(void* const* d_in, const int* in_sizes, int n_in,
                              void* d_out, int out_size, void* d_ws, size_t ws_size,
                              hipStream_t stream) {
  const float* x     = (const float*)d_in[0];
  const float* Wz    = (const float*)d_in[1];
  const float* bz    = (const float*)d_in[2];
  const float* Wh    = (const float*)d_in[3];
  const float* bh    = (const float*)d_in[4];
  const float* sbeta = (const float*)d_in[5];
  const float* gamma = (const float*)d_in[6];
  const float* lbeta = (const float*)d_in[7];
  float* out = (float*)d_out;

  char* ws = (char*)d_ws;
  u16* xb     = (u16*)ws;                         // 33,554,432 B
  u16* WT     = (u16*)(ws + 33554432);            //  4,194,304 B
  float* bb   = (float*)(ws + 37748736);          // 67,108,864 B
  float* Asum = (float*)(ws + 104857600);         //  2,097,152 B (512x1024 f32)
  float* Bsum = (float*)(ws + 106954752);         //  2,097,152 B
  float* hin  = (float*)(ws + 109051904);         //  2,097,152 B
  const size_t NEED_BASE = 111149056ull;
  const size_t NEED_FULL = NEED_BASE + 67108864ull;
  float* a_ptr = (ws_size >= NEED_FULL) ? (float*)(ws + NEED_BASE) : out;

  cvt_x_kernel<<<8192, 256, 0, stream>>>(x, xb);
  dim3 tw(32, 8), gw(32, 32, 2);
  cvt_w_kernel<<<gw, tw, 0, stream>>>(Wz, Wh, WT);
  gemm_dual_kernel<<<1024, 256, 0, stream>>>(xb, WT, bz, bh, a_ptr, bb, Asum, Bsum);
  chunk_scan_kernel<<<32, 256, 0, stream>>>(Asum, Bsum, hin);
  apply_ln_kernel<<<NCH, 256, 0, stream>>>(a_ptr, bb, hin, sbeta, gamma, lbeta, out);
}